// Round 6
// baseline (396.167 us; speedup 1.0000x reference)
//
#include <hip/hip_runtime.h>

static constexpr int NB = 512;     // batch
static constexpr int L  = 512;     // points per cloud
static constexpr int F  = 64;      // input features
static constexpr int H  = 128;     // hidden features
static constexpr float EPS = 1e-5f;

#define WT 132   // wlds row stride (floats), rows indexed by k (k-major, transposed W)
#define XT 68    // xlds row stride (floats), rows indexed by r

static const size_t NTOT = (size_t)NB * L * 2 * H;   // offset of g tail in out

// ---------------------------------------------------------------------------
// K0: zero the g tail of out (harness poisons d_out with 0xAA).
// ---------------------------------------------------------------------------
__global__ __launch_bounds__(256)
void k0_init(float* __restrict__ outp)
{
    const int i = blockIdx.x * 256 + threadIdx.x;
    if (i < NB * H) outp[NTOT + i] = 0.0f;
}

// ---------------------------------------------------------------------------
// K1: one block per (cloud n, 64-row chunk). GEMM(x W^T + b) -> LayerNorm ->
// ReLU -> coalesced y-store into first half of out rows; per-block masked max
// merged into the g tail of out via uint atomicMax (all values >= 0).
// Block 256 = 4 waves. Thread: tc=tid&31 -> h0=tc*4 (4 h), tr=tid>>5 -> 8 rows.
// ---------------------------------------------------------------------------
__global__ __launch_bounds__(256)
void k1_gemm_ln(const float* __restrict__ xp, const int* __restrict__ maskp,
                const float* __restrict__ Wp, const float* __restrict__ bp,
                const float* __restrict__ gp, const float* __restrict__ betap,
                float* __restrict__ outp)
{
    __shared__ float wlds[F * WT];     // 33792 B: wlds[k*WT + h] = W[h][k]
    __shared__ float xlds[64 * XT];    // 17408 B: xlds[r*XT + k]
    __shared__ float gsh[4][H];        // per-wave partial max

    const int bx  = blockIdx.x;
    const int n   = bx >> 3;
    const int c2  = bx & 7;
    const int rowbase = n * L + c2 * 64;
    const int tid = threadIdx.x;
    const int tc  = tid & 31;
    const int tr  = tid >> 5;
    const int h0  = tc * 4;
    const int r0  = tr * 8;
    const int wv_ = tid >> 6;

    // ---- stage W transposed: 2048 float4 reads, h-fast across lanes so the
    //      scalar LDS writes land on consecutive banks (2-way max = free).
    #pragma unroll
    for (int it = 0; it < 8; ++it) {
        const int i  = it * 256 + tid;     // 0..2047
        const int h  = i & 127;
        const int kg = i >> 7;             // float4 index along k: 0..15
        const float4 v = *(const float4*)(Wp + h * F + kg * 4);
        wlds[(kg * 4 + 0) * WT + h] = v.x;
        wlds[(kg * 4 + 1) * WT + h] = v.y;
        wlds[(kg * 4 + 2) * WT + h] = v.z;
        wlds[(kg * 4 + 3) * WT + h] = v.w;
    }
    // ---- stage x chunk: 1024 float4, fully coalesced, row-major.
    #pragma unroll
    for (int it = 0; it < 4; ++it) {
        const int i  = it * 256 + tid;     // 0..1023
        const int r  = i >> 4;
        const int kq = i & 15;
        *(float4*)&xlds[r * XT + kq * 4] =
            *(const float4*)(xp + (size_t)(rowbase + r) * F + kq * 4);
    }
    __syncthreads();

    // ---- register-tiled GEMM: acc[8 rows][4 h]
    float acc[8][4];
    #pragma unroll
    for (int ri = 0; ri < 8; ++ri)
        #pragma unroll
        for (int hc = 0; hc < 4; ++hc) acc[ri][hc] = 0.0f;

    #pragma unroll
    for (int k4 = 0; k4 < 16; ++k4) {
        // W rows k4*4..+3, cols h0..h0+3 (lanes tile all 32 banks uniformly)
        const float4 wv0 = *(const float4*)&wlds[(k4 * 4 + 0) * WT + h0];
        const float4 wv1 = *(const float4*)&wlds[(k4 * 4 + 1) * WT + h0];
        const float4 wv2 = *(const float4*)&wlds[(k4 * 4 + 2) * WT + h0];
        const float4 wv3 = *(const float4*)&wlds[(k4 * 4 + 3) * WT + h0];
        #pragma unroll
        for (int ri = 0; ri < 8; ++ri) {
            const float4 xv = *(const float4*)&xlds[(r0 + ri) * XT + k4 * 4];  // broadcast
            acc[ri][0] += xv.x * wv0.x; acc[ri][1] += xv.x * wv0.y;
            acc[ri][2] += xv.x * wv0.z; acc[ri][3] += xv.x * wv0.w;
            acc[ri][0] += xv.y * wv1.x; acc[ri][1] += xv.y * wv1.y;
            acc[ri][2] += xv.y * wv1.z; acc[ri][3] += xv.y * wv1.w;
            acc[ri][0] += xv.z * wv2.x; acc[ri][1] += xv.z * wv2.y;
            acc[ri][2] += xv.z * wv2.z; acc[ri][3] += xv.z * wv2.w;
            acc[ri][0] += xv.w * wv3.x; acc[ri][1] += xv.w * wv3.y;
            acc[ri][2] += xv.w * wv3.z; acc[ri][3] += xv.w * wv3.w;
        }
    }

    // ---- per-h params
    float bias[4], gam[4], bet[4];
    #pragma unroll
    for (int hc = 0; hc < 4; ++hc) {
        bias[hc] = bp[h0 + hc];
        gam[hc]  = gp[h0 + hc];
        bet[hc]  = betap[h0 + hc];
    }

    float gmax[4] = {0.0f, 0.0f, 0.0f, 0.0f};

    // ---- bias + LayerNorm + ReLU + coalesced store + masked max
    #pragma unroll
    for (int ri = 0; ri < 8; ++ri) {
        const int grow = rowbase + r0 + ri;
        float s = 0.0f, q = 0.0f;
        #pragma unroll
        for (int hc = 0; hc < 4; ++hc) {
            const float v = acc[ri][hc] + bias[hc];
            acc[ri][hc] = v;
            s += v; q += v * v;
        }
        #pragma unroll
        for (int o = 1; o < 32; o <<= 1) {       // sum across the 32 tc lanes
            s += __shfl_xor(s, o);
            q += __shfl_xor(q, o);
        }
        const float mu  = s * (1.0f / 128.0f);
        const float var = q * (1.0f / 128.0f) - mu * mu;
        const float rsg = rsqrtf(var + EPS);
        const int   mk  = maskp[grow];

        float4 y4;
        float yv[4];
        #pragma unroll
        for (int hc = 0; hc < 4; ++hc) {
            float y = (acc[ri][hc] - mu) * rsg * gam[hc] + bet[hc];
            y = fmaxf(y, 0.0f);
            yv[hc] = y;
            if (mk != 0) gmax[hc] = fmaxf(gmax[hc], y);
        }
        y4.x = yv[0]; y4.y = yv[1]; y4.z = yv[2]; y4.w = yv[3];
        *(float4*)(outp + (size_t)grow * (2 * H) + h0) = y4;   // half-wave: 512B contig
    }

    // ---- block-level masked max -> atomicMax into the g tail (uint bits)
    #pragma unroll
    for (int hc = 0; hc < 4; ++hc)
        gmax[hc] = fmaxf(gmax[hc], __shfl_xor(gmax[hc], 32));  // combine tr pairs in wave
    if ((tid & 63) < 32) {
        #pragma unroll
        for (int hc = 0; hc < 4; ++hc)
            gsh[wv_][h0 + hc] = gmax[hc];
    }
    __syncthreads();
    if (tid < H) {
        const float m = fmaxf(fmaxf(gsh[0][tid], gsh[1][tid]),
                              fmaxf(gsh[2][tid], gsh[3][tid]));
        // non-negative fp32: bit pattern is monotone under unsigned compare
        atomicMax((unsigned*)(outp + NTOT + (size_t)n * H + tid),
                  __float_as_uint(m));
    }
}

// ---------------------------------------------------------------------------
// K2: one block per (n, 64-row chunk): read the cloud's final g from the out
// tail (L2-hot, 512B per cloud) and broadcast into the second half of rows.
// ---------------------------------------------------------------------------
__global__ __launch_bounds__(256)
void k2_bcast(float* __restrict__ outp)
{
    const int bx  = blockIdx.x;
    const int n   = bx >> 3;
    const int c2  = bx & 7;
    const int tid = threadIdx.x;
    const int tc  = tid & 31;
    const int tr  = tid >> 5;
    const int h0  = tc * 4;

    const float4 g4 = *(const float4*)(outp + NTOT + (size_t)n * H + h0);

    #pragma unroll
    for (int ri = 0; ri < 8; ++ri) {
        const int l = c2 * 64 + tr * 8 + ri;
        *(float4*)(outp + ((size_t)n * L + l) * (2 * H) + H + h0) = g4;
    }
}

extern "C" void kernel_launch(void* const* d_in, const int* in_sizes, int n_in,
                              void* d_out, int out_size, void* d_ws, size_t ws_size,
                              hipStream_t stream)
{
    (void)in_sizes; (void)n_in; (void)out_size; (void)d_ws; (void)ws_size;
    const float* x     = (const float*)d_in[0];
    const int*   mask  = (const int*)d_in[1];
    const float* W     = (const float*)d_in[2];
    const float* b     = (const float*)d_in[3];
    const float* gamma = (const float*)d_in[4];
    const float* beta  = (const float*)d_in[5];
    float* out = (float*)d_out;

    k0_init<<<dim3((NB * H + 255) / 256), dim3(256), 0, stream>>>(out);
    k1_gemm_ln<<<dim3(NB * 8), dim3(256), 0, stream>>>(
        x, mask, W, b, gamma, beta, out);
    k2_bcast<<<dim3(NB * 8), dim3(256), 0, stream>>>(out);
}

// Round 7
// 346.963 us; speedup vs baseline: 1.1418x; 1.1418x over previous
//
#include <hip/hip_runtime.h>

typedef unsigned int u32;
typedef unsigned short u16;
using s16x8 = __attribute__((ext_vector_type(8))) short;   // 8 bf16 (4 VGPRs)
using f32x4 = __attribute__((ext_vector_type(4))) float;

static constexpr int NB = 512;     // batch
static constexpr int L  = 512;     // points per cloud
static constexpr int F  = 64;      // input features
static constexpr int H  = 128;     // hidden features
static constexpr float EPS = 1e-5f;
static const size_t NTOT = (size_t)NB * L * 2 * H;   // g tail offset in out

// round-to-nearest-even fp32 -> bf16 bits
__device__ __forceinline__ u32 bf_rne(float f) {
    u32 u = __float_as_uint(f);
    return (u + 0x7fffu + ((u >> 16) & 1u)) >> 16;
}

// ---------------------------------------------------------------------------
// K0: zero the g tail of out (harness poisons d_out with 0xAA).
// ---------------------------------------------------------------------------
__global__ __launch_bounds__(256)
void k0_init(float* __restrict__ outp)
{
    const int i = blockIdx.x * 256 + threadIdx.x;
    if (i < NB * H) outp[NTOT + i] = 0.0f;
}

// ---------------------------------------------------------------------------
// K1: one block per (cloud n, 64-row chunk); 4 waves, each owning 16 rows.
// Split-bf16 MFMA GEMM (x W^T) -> +bias -> LayerNorm -> ReLU -> y-store;
// per-block masked max -> atomicMax into g tail (uint bits, values >= 0).
// W converted once per block into bf16 hi/lo B-fragments in LDS (frag-ordered,
// conflict-free ds_read_b128). x: global->register A-fragments, no LDS.
// ---------------------------------------------------------------------------
__global__ __launch_bounds__(256)
void k1_gemm_ln(const float* __restrict__ xp, const int* __restrict__ maskp,
                const float* __restrict__ Wp, const float* __restrict__ bp,
                const float* __restrict__ gp, const float* __restrict__ betap,
                float* __restrict__ outp)
{
    __shared__ u16  whi[8192];     // 16 KB: B-frag-ordered W hi
    __shared__ u16  wlo[8192];     // 16 KB: B-frag-ordered W lo
    __shared__ float gsh[4][H];    // per-wave masked-max partials

    const int bx    = blockIdx.x;
    const int n     = bx >> 3;
    const int chunk = bx & 7;
    const int tid   = threadIdx.x;
    const int w     = tid >> 6;
    const int lane  = tid & 63;
    const int m     = lane & 15;
    const int q     = lane >> 4;

    // ---- stage W as bf16 hi/lo fragments. Group g (0..1023) = frag (t,s) x lane:
    //      t=g>>7, s=(g>>6)&1, ln=g&63; element j: W[t*16+(ln&15)][s*32+(ln>>4)*8+j]
    #pragma unroll
    for (int it = 0; it < 4; ++it) {
        const int g  = it * 256 + tid;
        const int t  = g >> 7;
        const int s  = (g >> 6) & 1;
        const int ln = g & 63;
        const int mm = ln & 15;
        const int qq = ln >> 4;
        const float* src = Wp + (t * 16 + mm) * F + s * 32 + qq * 8;
        const float4 a = *(const float4*)src;
        const float4 b = *(const float4*)(src + 4);
        const float xv[8] = {a.x, a.y, a.z, a.w, b.x, b.y, b.z, b.w};
        u32 hi[8], lo[8];
        #pragma unroll
        for (int j = 0; j < 8; ++j) {
            hi[j] = bf_rne(xv[j]);
            const float hf = __uint_as_float(hi[j] << 16);
            lo[j] = bf_rne(xv[j] - hf);
        }
        uint4 ph, pl;
        ph.x = hi[0] | (hi[1] << 16); ph.y = hi[2] | (hi[3] << 16);
        ph.z = hi[4] | (hi[5] << 16); ph.w = hi[6] | (hi[7] << 16);
        pl.x = lo[0] | (lo[1] << 16); pl.y = lo[2] | (lo[3] << 16);
        pl.z = lo[4] | (lo[5] << 16); pl.w = lo[6] | (lo[7] << 16);
        *(uint4*)&whi[g * 8] = ph;
        *(uint4*)&wlo[g * 8] = pl;
    }

    // ---- A fragments: x rows rb..rb+15, split hi/lo (global -> regs, no LDS)
    const int rb = n * L + chunk * 64 + w * 16;
    s16x8 Ahi[2], Alo[2];
    #pragma unroll
    for (int s = 0; s < 2; ++s) {
        const float* xs = xp + (size_t)(rb + m) * F + s * 32 + q * 8;
        const float4 a = *(const float4*)xs;
        const float4 b = *(const float4*)(xs + 4);
        const float xv[8] = {a.x, a.y, a.z, a.w, b.x, b.y, b.z, b.w};
        #pragma unroll
        for (int j = 0; j < 8; ++j) {
            const u32 hb = bf_rne(xv[j]);
            const float hf = __uint_as_float(hb << 16);
            Ahi[s][j] = (short)hb;
            Alo[s][j] = (short)bf_rne(xv[j] - hf);
        }
    }
    __syncthreads();

    // ---- MFMA: 8 h-tiles x 2 k-steps x 3 split terms
    f32x4 acc[8] = {};
    #pragma unroll
    for (int t = 0; t < 8; ++t) {
        #pragma unroll
        for (int s = 0; s < 2; ++s) {
            const s16x8 Bh = *(const s16x8*)&whi[((t * 2 + s) * 64 + lane) * 8];
            const s16x8 Bl = *(const s16x8*)&wlo[((t * 2 + s) * 64 + lane) * 8];
            acc[t] = __builtin_amdgcn_mfma_f32_16x16x32_bf16(Ahi[s], Bh, acc[t], 0, 0, 0);
            acc[t] = __builtin_amdgcn_mfma_f32_16x16x32_bf16(Alo[s], Bh, acc[t], 0, 0, 0);
            acc[t] = __builtin_amdgcn_mfma_f32_16x16x32_bf16(Ahi[s], Bl, acc[t], 0, 0, 0);
        }
    }

    // ---- per-column params (h = t*16 + m); L2/L1-hot scalar loads
    float bias[8], gam[8], bet[8];
    #pragma unroll
    for (int t = 0; t < 8; ++t) {
        const int h = t * 16 + m;
        bias[t] = bp[h];
        gam[t]  = gp[h];
        bet[t]  = betap[h];
    }
    #pragma unroll
    for (int t = 0; t < 8; ++t)
        #pragma unroll
        for (int r = 0; r < 4; ++r)
            acc[t][r] += bias[t];

    // ---- LayerNorm stats. C/D layout: col=lane&15, row=q*4+reg.
    float sum[4] = {0, 0, 0, 0}, sq[4] = {0, 0, 0, 0};
    #pragma unroll
    for (int t = 0; t < 8; ++t)
        #pragma unroll
        for (int r = 0; r < 4; ++r) {
            const float v = acc[t][r];
            sum[r] += v; sq[r] += v * v;
        }
    #pragma unroll
    for (int r = 0; r < 4; ++r) {
        #pragma unroll
        for (int o = 1; o < 16; o <<= 1) {
            sum[r] += __shfl_xor(sum[r], o);
            sq[r]  += __shfl_xor(sq[r],  o);
        }
    }
    float mu[4], rs[4];
    #pragma unroll
    for (int r = 0; r < 4; ++r) {
        mu[r] = sum[r] * (1.0f / 128.0f);
        const float var = sq[r] * (1.0f / 128.0f) - mu[r] * mu[r];
        rs[r] = rsqrtf(var + EPS);
    }

    int mk[4];
    #pragma unroll
    for (int r = 0; r < 4; ++r) mk[r] = maskp[rb + q * 4 + r];

    // ---- normalize, relu, store y (64B-aligned quad segments), masked max
    float gmax[8];
    #pragma unroll
    for (int t = 0; t < 8; ++t) {
        float gm = 0.0f;
        #pragma unroll
        for (int r = 0; r < 4; ++r) {
            float y = (acc[t][r] - mu[r]) * rs[r] * gam[t] + bet[t];
            y = fmaxf(y, 0.0f);
            outp[(size_t)(rb + q * 4 + r) * (2 * H) + t * 16 + m] = y;
            if (mk[r] != 0) gm = fmaxf(gm, y);
        }
        gm = fmaxf(gm, __shfl_xor(gm, 16));
        gm = fmaxf(gm, __shfl_xor(gm, 32));
        gmax[t] = gm;
    }

    if (q == 0) {
        #pragma unroll
        for (int t = 0; t < 8; ++t)
            gsh[w][t * 16 + m] = gmax[t];
    }
    __syncthreads();
    if (tid < H) {
        const float mx = fmaxf(fmaxf(gsh[0][tid], gsh[1][tid]),
                               fmaxf(gsh[2][tid], gsh[3][tid]));
        atomicMax((u32*)(outp + NTOT + (size_t)n * H + tid), __float_as_uint(mx));
    }
}

// ---------------------------------------------------------------------------
// K2: one block per (n, 64-row chunk): read final g from the out tail
// (L2-hot, 512 B per cloud) and broadcast into the second half of rows.
// ---------------------------------------------------------------------------
__global__ __launch_bounds__(256)
void k2_bcast(float* __restrict__ outp)
{
    const int bx  = blockIdx.x;
    const int n   = bx >> 3;
    const int c2  = bx & 7;
    const int tid = threadIdx.x;
    const int tc  = tid & 31;
    const int tr  = tid >> 5;
    const int h0  = tc * 4;

    const float4 g4 = *(const float4*)(outp + NTOT + (size_t)n * H + h0);

    #pragma unroll
    for (int ri = 0; ri < 8; ++ri) {
        const int l = c2 * 64 + tr * 8 + ri;
        *(float4*)(outp + ((size_t)n * L + l) * (2 * H) + H + h0) = g4;
    }
}

extern "C" void kernel_launch(void* const* d_in, const int* in_sizes, int n_in,
                              void* d_out, int out_size, void* d_ws, size_t ws_size,
                              hipStream_t stream)
{
    (void)in_sizes; (void)n_in; (void)out_size; (void)d_ws; (void)ws_size;
    const float* x     = (const float*)d_in[0];
    const int*   mask  = (const int*)d_in[1];
    const float* W     = (const float*)d_in[2];
    const float* b     = (const float*)d_in[3];
    const float* gamma = (const float*)d_in[4];
    const float* beta  = (const float*)d_in[5];
    float* out = (float*)d_out;

    k0_init<<<dim3((NB * H + 255) / 256), dim3(256), 0, stream>>>(out);
    k1_gemm_ln<<<dim3(NB * 8), dim3(256), 0, stream>>>(
        x, mask, W, b, gamma, beta, out);
    k2_bcast<<<dim3(NB * 8), dim3(256), 0, stream>>>(out);
}